// Round 1
// baseline (389.133 us; speedup 1.0000x reference)
//
#include <hip/hip_runtime.h>

#define B_ROWS 262144
#define T_COLS 80
#define STEPS 30
#define DT 0.1f

__global__ __launch_bounds__(256) void traj_idm_kernel(
    const float* __restrict__ params,
    const float* __restrict__ sv_v1,
    const float* __restrict__ h1,
    const float* __restrict__ dv1,
    const float* __restrict__ sv_Y1,
    const float* __restrict__ lv_Y_seq1,
    const float* __restrict__ lv_v_seq1,
    float* __restrict__ out)
{
    const int b = blockIdx.x * blockDim.x + threadIdx.x;
    if (b >= B_ROWS) return;

    // params are wave-uniform -> compiler emits scalar loads
    const float s0   = params[0];
    const float Thw  = params[1];
    const float pa   = params[2];
    const float pb   = params[3];
    const float v0   = params[4];
    const float inv2sab = 1.0f / (2.0f * sqrtf(pa * pb));
    const float inv_v0  = 1.0f / v0;
    const float inv_dt  = 1.0f / DT;

    const long base = (long)b * T_COLS;

    float v    = sv_v1 [base + 49];
    float gap  = h1    [base + 49];
    float delv = dv1   [base + 49];
    float y    = sv_Y1 [base + 49];

    // columns 50..79: byte offset b*320+200 -> 8B aligned, use float2
    const float2* __restrict__ lvY2 = (const float2*)(lv_Y_seq1 + base + 50);
    const float2* __restrict__ lvv2 = (const float2*)(lv_v_seq1 + base + 50);

    float ys[STEPS];

    #pragma unroll
    for (int p = 0; p < STEPS / 2; ++p) {
        const float2 lvY = lvY2[p];
        const float2 lvv = lvv2[p];
        #pragma unroll
        for (int s = 0; s < 2; ++s) {
            const float lvY_i = s ? lvY.y : lvY.x;
            const float lvv_i = s ? lvv.y : lvv.x;

            const float s_star = s0 + fmaxf(v * Thw + v * delv * inv2sab, 0.0f);
            const float r  = v * inv_v0;
            const float r2 = r * r;
            const float q  = s_star / gap;
            const float a_calc = pa * (1.0f - r2 * r2 - q * q);
            const float v2 = v + a_calc * DT;
            const float a_t = (v2 <= 0.0f) ? (-v * inv_dt) : a_calc;

            v    = v + a_t * DT;
            delv = v - lvv_i;
            y    = y + v * DT;
            gap  = lvY_i - y;
            ys[2 * p + s] = y;
        }
    }

    // out[b*30 + t]; b*30 is even -> 8B aligned, use float2 stores
    float2* __restrict__ o2 = (float2*)(out + (long)b * STEPS);
    #pragma unroll
    for (int p = 0; p < STEPS / 2; ++p) {
        float2 w;
        w.x = ys[2 * p];
        w.y = ys[2 * p + 1];
        o2[p] = w;
    }
}

extern "C" void kernel_launch(void* const* d_in, const int* in_sizes, int n_in,
                              void* d_out, int out_size, void* d_ws, size_t ws_size,
                              hipStream_t stream) {
    const float* params    = (const float*)d_in[0];
    const float* sv_v1     = (const float*)d_in[1];
    const float* h1        = (const float*)d_in[2];
    const float* dv1       = (const float*)d_in[3];
    const float* sv_Y1     = (const float*)d_in[4];
    const float* lv_Y_seq1 = (const float*)d_in[5];
    const float* lv_v_seq1 = (const float*)d_in[6];
    float* out = (float*)d_out;

    const int threads = 256;
    const int blocks = (B_ROWS + threads - 1) / threads;
    traj_idm_kernel<<<blocks, threads, 0, stream>>>(
        params, sv_v1, h1, dv1, sv_Y1, lv_Y_seq1, lv_v_seq1, out);
}

// Round 2
// 376.514 us; speedup vs baseline: 1.0335x; 1.0335x over previous
//
#include <hip/hip_runtime.h>

#define B_ROWS 262144
#define T_COLS 80
#define STEPS 30
#define DT 0.1f
#define RPB 128          // rows per block
#define THREADS 256
#define IN_PAD 33        // 32 staged cols + 1 pad -> conflict-free compute reads

__global__ __launch_bounds__(THREADS) void traj_idm_kernel(
    const float* __restrict__ params,
    const float* __restrict__ sv_v1,
    const float* __restrict__ h1,
    const float* __restrict__ dv1,
    const float* __restrict__ sv_Y1,
    const float* __restrict__ lv_Y_seq1,
    const float* __restrict__ lv_v_seq1,
    float* __restrict__ out)
{
    __shared__ float sY[RPB][IN_PAD];
    __shared__ float sV[RPB][IN_PAD];
    __shared__ __align__(16) float sOut[RPB * STEPS];

    const int t  = threadIdx.x;
    const int r0 = blockIdx.x * RPB;

    // --- irreducible col-49 gathers: issue first, latency overlaps staging ---
    float v = 0.f, gap = 1.f, delv = 0.f, y = 0.f;
    if (t < RPB) {
        const long base = (long)(r0 + t) * T_COLS + 49;
        v    = sv_v1 [base];
        gap  = h1    [base];
        delv = dv1   [base];
        y    = sv_Y1 [base];
    }

    // --- coalesced staging of cols 48..79 (16B-aligned, 128 B/row fully used) ---
    // 128 rows x 8 float4 per array = 1024 float4; 256 threads -> 4 iters
    #pragma unroll
    for (int i = 0; i < 4; ++i) {
        const int idx = i * THREADS + t;      // 0..1023
        const int row = idx >> 3;
        const int sub = idx & 7;
        const long goff = (long)(r0 + row) * T_COLS + 48 + sub * 4;
        const float4 dy = *(const float4*)(lv_Y_seq1 + goff);
        const float4 dv4 = *(const float4*)(lv_v_seq1 + goff);
        const int c = sub * 4;
        sY[row][c + 0] = dy.x;  sY[row][c + 1] = dy.y;
        sY[row][c + 2] = dy.z;  sY[row][c + 3] = dy.w;
        sV[row][c + 0] = dv4.x; sV[row][c + 1] = dv4.y;
        sV[row][c + 2] = dv4.z; sV[row][c + 3] = dv4.w;
    }
    __syncthreads();

    // --- compute: 30-step IDM recurrence, one thread per row ---
    if (t < RPB) {
        const float s0   = params[0];
        const float Thw  = params[1];
        const float pa   = params[2];
        const float pb   = params[3];
        const float v0   = params[4];
        const float inv2sab = 1.0f / (2.0f * sqrtf(pa * pb));
        const float inv_v0  = 1.0f / v0;
        const float inv_dt  = 1.0f / DT;

        #pragma unroll
        for (int s = 0; s < STEPS; ++s) {
            const float lvY_i = sY[t][2 + s];   // col 50+s
            const float lvv_i = sV[t][2 + s];

            const float s_star = s0 + fmaxf(v * Thw + v * delv * inv2sab, 0.0f);
            const float r  = v * inv_v0;
            const float r2 = r * r;
            const float q  = s_star / gap;
            const float a_calc = pa * (1.0f - r2 * r2 - q * q);
            const float v2 = v + a_calc * DT;
            const float a_t = (v2 <= 0.0f) ? (-v * inv_dt) : a_calc;

            v    = v + a_t * DT;
            delv = v - lvv_i;
            y    = y + v * DT;
            gap  = lvY_i - y;
            sOut[t * STEPS + s] = y;
        }
    }
    __syncthreads();

    // --- fully-coalesced output store: block region is contiguous & 16B-aligned ---
    const float4* so4 = (const float4*)sOut;
    float4* go4 = (float4*)(out + (long)r0 * STEPS);
    #pragma unroll
    for (int k = t; k < RPB * STEPS / 4; k += THREADS)   // 960 float4
        go4[k] = so4[k];
}

extern "C" void kernel_launch(void* const* d_in, const int* in_sizes, int n_in,
                              void* d_out, int out_size, void* d_ws, size_t ws_size,
                              hipStream_t stream) {
    const float* params    = (const float*)d_in[0];
    const float* sv_v1     = (const float*)d_in[1];
    const float* h1        = (const float*)d_in[2];
    const float* dv1       = (const float*)d_in[3];
    const float* sv_Y1     = (const float*)d_in[4];
    const float* lv_Y_seq1 = (const float*)d_in[5];
    const float* lv_v_seq1 = (const float*)d_in[6];
    float* out = (float*)d_out;

    const int blocks = B_ROWS / RPB;   // 2048
    traj_idm_kernel<<<blocks, THREADS, 0, stream>>>(
        params, sv_v1, h1, dv1, sv_Y1, lv_Y_seq1, lv_v_seq1, out);
}